// Round 8
// baseline (422.768 us; speedup 1.0000x reference)
//
#include <hip/hip_runtime.h>
#include <math.h>

namespace {

typedef _Float16 half8 __attribute__((ext_vector_type(8)));
typedef float floatx4 __attribute__((ext_vector_type(4)));

constexpr int kS   = 1024;
constexpr int kD   = 64;
constexpr int kPad = 72;   // 144 B row stride: 16B-aligned (b128-safe), 2-way phase
constexpr float kLog2e = 1.4426950408889634f;
constexpr float kThr   = 8.0f;  // defer-rescale threshold (log2 space)

union H4 { _Float16 h[4]; uint2 u2; };

__device__ __forceinline__ float fast_exp2(float x) {
#if __has_builtin(__builtin_amdgcn_exp2f)
  return __builtin_amdgcn_exp2f(x);
#else
  return exp2f(x);
#endif
}

__device__ __forceinline__ float fast_rcp(float x) {
#if __has_builtin(__builtin_amdgcn_rcpf)
  return __builtin_amdgcn_rcpf(x);
#else
  return 1.0f / x;
#endif
}

// 4 waves/SIMD requires 32-row waves (work = 4096 waves) AND <=128 regs/wave
// total (unified VGPR+AGPR; R7 proved (512,4) spills at ~150 demand).
// Key change: speculative per-mt P packing. S[mt] is transient (4 regs);
// pj = exp2(S - m_stale) packed immediately into f16 Pp[g][mt] (16 regs vs 32
// for full S). On the rare defer-rescale trigger (first ~2 tiles) the mt-loop
// re-runs with the new max -> bit-identical math to round 6 (absmax canary
// 0.03125). fk LDS reads stay shared across both q-groups (mt-outer).
// Live set ~94 arch + 32 AGPR ~= 126 <= 128.
__global__ __launch_bounds__(512, 4)
void fa_mfma_kernel(const float* __restrict__ qg, const float* __restrict__ kg,
                    const float* __restrict__ vg, float* __restrict__ og) {
  __shared__ __align__(16) _Float16 sK [2][64][kPad];  // K tiles [buf][key][d]
  __shared__ __align__(16) _Float16 sVt[2][64][kPad];  // V^T tiles [buf][d][key]
  __shared__ __align__(16) _Float16 sP [256][kPad];    // P [qrow(block)][key]

  const int tid  = threadIdx.x;
  const int lane = tid & 63;
  const int w    = __builtin_amdgcn_readfirstlane(tid >> 6);  // 0..7
  const int quad = lane >> 4;
  const int r    = lane & 15;

  // XCD swizzle for 512 blocks: batch b's 4 q-tile blocks -> same XCD (i%8).
  const int blk = blockIdx.x;
  const int b     = (blk & 7) + 8 * (blk >> 5);  // batch 0..127
  const int qbase = ((blk >> 3) & 3) * 256;      // q-tile 0..3 (256 rows each)

  const float* qb = qg + (size_t)b * kS * kD;
  const float* kb = kg + (size_t)b * kS * kD;
  const float* vb = vg + (size_t)b * kS * kD;
  float*       ob = og + (size_t)b * kS * kD;

  // ---- Q fragments direct from global: hi/lo f16 split, pre-scaled log2e ----
  half8 fqh[2][2], fql[2][2];  // [ntq][ks]
#pragma unroll
  for (int ntq = 0; ntq < 2; ++ntq)
#pragma unroll
    for (int ks = 0; ks < 2; ++ks) {
      const float* src =
          qb + (size_t)(qbase + w * 32 + ntq * 16 + r) * kD + ks * 32 + quad * 8;
      float4 a = ((const float4*)src)[0];
      float4 c = ((const float4*)src)[1];
      float f[8] = {a.x, a.y, a.z, a.w, c.x, c.y, c.z, c.w};
#pragma unroll
      for (int j = 0; j < 8; ++j) {
        float x = f[j] * kLog2e;
        _Float16 h = (_Float16)x;
        fqh[ntq][ks][j] = h;
        fql[ntq][ks][j] = (_Float16)(x - (float)h);
      }
    }

  float m_i[2] = {-INFINITY, -INFINITY}, l_i[2] = {0.f, 0.f};
  floatx4 O[2][4];
#pragma unroll
  for (int a = 0; a < 2; ++a)
#pragma unroll
    for (int c = 0; c < 4; ++c) O[a][c] = floatx4{0.f, 0.f, 0.f, 0.f};

  // Staging roles (R7-verified): waves 0-3 (tid 0-255) stage K, 4-7 stage V.
  const bool kRole = (w < 4);
  const int st = tid & 255;
  const int krow  = st >> 2, kc0 = (st & 3) * 16;  // K row-major copy
  const int vkey4 = (st & 15) * 4;                 // V: 4 consecutive keys
  const int vd0   = (st >> 4) * 4;                 //    x 4 dims sub-tile
  float4 buf[4];

  auto load_kv = [&](int kt) {
    if (kRole) {
      const float4* ksrc =
          (const float4*)(kb + (size_t)(kt * 64 + krow) * kD + kc0);
#pragma unroll
      for (int g = 0; g < 4; ++g) buf[g] = ksrc[g];
    } else {
#pragma unroll
      for (int kk = 0; kk < 4; ++kk)
        buf[kk] = *(const float4*)(vb + (size_t)(kt * 64 + vkey4 + kk) * kD + vd0);
    }
  };
  auto stage = [&](int bi) {
    if (kRole) {
#pragma unroll
      for (int g = 0; g < 4; ++g) {
        float t[4] = {buf[g].x, buf[g].y, buf[g].z, buf[g].w};
        H4 hk;
#pragma unroll
        for (int j = 0; j < 4; ++j) hk.h[j] = (_Float16)t[j];
        *(uint2*)&sK[bi][krow][kc0 + g * 4] = hk.u2;
      }
    } else {
      float tv[4][4];
#pragma unroll
      for (int kk = 0; kk < 4; ++kk) {
        tv[kk][0] = buf[kk].x; tv[kk][1] = buf[kk].y;
        tv[kk][2] = buf[kk].z; tv[kk][3] = buf[kk].w;
      }
#pragma unroll
      for (int j = 0; j < 4; ++j) {
        H4 hv;
#pragma unroll
        for (int kk = 0; kk < 4; ++kk) hv.h[kk] = (_Float16)tv[kk][j];
        *(uint2*)&sVt[bi][vd0 + j][vkey4] = hv.u2;
      }
    }
  };

  // Prologue: LDS buf0 <- tile 0; regs <- tile 1.
  load_kv(0);
  stage(0);
  load_kv(1);

  for (int kt = 0; kt < kS / 64; ++kt) {
    const int cur = kt & 1, nxt = cur ^ 1;
    __syncthreads();  // buf[cur] staged & prior reads of buf[nxt] done
    stage(nxt);                // tile kt+1 -> other buffer (overlaps compute)
    load_kv((kt + 2) & 15);    // regs <- tile kt+2 (wrap harmless)

    // ---- QK + speculative pack: S[mt] transient, P packed with stale max ----
    float rs[2]   = {0.f, 0.f};
    float pmax[2] = {-INFINITY, -INFINITY};
    uint2 Pp[2][4];
#pragma unroll
    for (int mt = 0; mt < 4; ++mt) {
      half8 fk0 = *(const half8*)&sK[cur][mt * 16 + r][quad * 8];
      half8 fk1 = *(const half8*)&sK[cur][mt * 16 + r][32 + quad * 8];
#pragma unroll
      for (int g = 0; g < 2; ++g) {
        floatx4 s = {0.f, 0.f, 0.f, 0.f};
        s = __builtin_amdgcn_mfma_f32_16x16x32_f16(fk0, fqh[g][0], s, 0, 0, 0);
        s = __builtin_amdgcn_mfma_f32_16x16x32_f16(fk1, fqh[g][1], s, 0, 0, 0);
        s = __builtin_amdgcn_mfma_f32_16x16x32_f16(fk0, fql[g][0], s, 0, 0, 0);
        s = __builtin_amdgcn_mfma_f32_16x16x32_f16(fk1, fql[g][1], s, 0, 0, 0);
        H4 hp;
#pragma unroll
        for (int j = 0; j < 4; ++j) {
          const float sj = s[j];
          pmax[g] = fmaxf(pmax[g], sj);
          const float pj = fast_exp2(sj - m_i[g]);
          rs[g] += pj;
          hp.h[j] = (_Float16)pj;
        }
        Pp[g][mt] = hp.u2;
      }
    }

    // ---- defer-rescale check; rare path recomputes with the new max ----
    float tm[2];
#pragma unroll
    for (int g = 0; g < 2; ++g) {
      float t = pmax[g];
      t = fmaxf(t, __shfl_xor(t, 16, 64));
      t = fmaxf(t, __shfl_xor(t, 32, 64));
      tm[g] = t;
    }
    const unsigned long long need =
        __ballot(tm[0] > m_i[0] + kThr || tm[1] > m_i[1] + kThr);
    if (need) {
      float alpha[2];
#pragma unroll
      for (int g = 0; g < 2; ++g) {
        const float mn = fmaxf(m_i[g], tm[g]);
        alpha[g] = fast_exp2(m_i[g] - mn);  // first tile: exp2(-inf)=0
        m_i[g] = mn;
        l_i[g] *= alpha[g];
      }
#pragma unroll
      for (int g = 0; g < 2; ++g)
#pragma unroll
        for (int j = 0; j < 4; ++j) {
          const float a = __shfl(alpha[g], quad * 4 + j, 64);
#pragma unroll
          for (int nd = 0; nd < 4; ++nd) O[g][nd][j] *= a;
        }
      // Recompute pass (identical math, new m_i). fk re-read from LDS.
      rs[0] = 0.f; rs[1] = 0.f;
#pragma unroll
      for (int mt = 0; mt < 4; ++mt) {
        half8 fk0 = *(const half8*)&sK[cur][mt * 16 + r][quad * 8];
        half8 fk1 = *(const half8*)&sK[cur][mt * 16 + r][32 + quad * 8];
#pragma unroll
        for (int g = 0; g < 2; ++g) {
          floatx4 s = {0.f, 0.f, 0.f, 0.f};
          s = __builtin_amdgcn_mfma_f32_16x16x32_f16(fk0, fqh[g][0], s, 0, 0, 0);
          s = __builtin_amdgcn_mfma_f32_16x16x32_f16(fk1, fqh[g][1], s, 0, 0, 0);
          s = __builtin_amdgcn_mfma_f32_16x16x32_f16(fk0, fql[g][0], s, 0, 0, 0);
          s = __builtin_amdgcn_mfma_f32_16x16x32_f16(fk1, fql[g][1], s, 0, 0, 0);
          H4 hp;
#pragma unroll
          for (int j = 0; j < 4; ++j) {
            const float pj = fast_exp2(s[j] - m_i[g]);
            rs[g] += pj;
            hp.h[j] = (_Float16)pj;
          }
          Pp[g][mt] = hp.u2;
        }
      }
    }

    // ---- finalize l; write packed P to LDS ----
#pragma unroll
    for (int g = 0; g < 2; ++g) {
      float t = rs[g];
      t += __shfl_xor(t, 16, 64);
      t += __shfl_xor(t, 32, 64);
      l_i[g] += t;
#pragma unroll
      for (int mt = 0; mt < 4; ++mt)
        *(uint2*)&sP[w * 32 + g * 16 + r][mt * 16 + quad * 4] = Pp[g][mt];
    }

    // ---- O += P·V ----
    __builtin_amdgcn_s_setprio(1);
#pragma unroll
    for (int ks = 0; ks < 2; ++ks) {
      half8 fp0 = *(const half8*)&sP[w * 32 + 0 * 16 + r][ks * 32 + quad * 8];
      half8 fp1 = *(const half8*)&sP[w * 32 + 1 * 16 + r][ks * 32 + quad * 8];
#pragma unroll
      for (int nd = 0; nd < 4; ++nd) {
        half8 fv = *(const half8*)&sVt[cur][nd * 16 + r][ks * 32 + quad * 8];
        O[0][nd] = __builtin_amdgcn_mfma_f32_16x16x32_f16(fp0, fv, O[0][nd], 0, 0, 0);
        O[1][nd] = __builtin_amdgcn_mfma_f32_16x16x32_f16(fp1, fv, O[1][nd], 0, 0, 0);
      }
    }
    __builtin_amdgcn_s_setprio(0);
  }

  // ---- epilogue: out[qrow][dim] = O / l ----
#pragma unroll
  for (int mtq = 0; mtq < 2; ++mtq)
#pragma unroll
    for (int j = 0; j < 4; ++j) {
      const float lrow = __shfl(l_i[mtq], quad * 4 + j, 64);
      const float linv = fast_rcp(lrow);
      float* dst =
          ob + (size_t)(qbase + w * 32 + mtq * 16 + quad * 4 + j) * kD + r;
#pragma unroll
      for (int nd = 0; nd < 4; ++nd) dst[nd * 16] = O[mtq][nd][j] * linv;
    }
}

}  // namespace

extern "C" void kernel_launch(void* const* d_in, const int* in_sizes, int n_in,
                              void* d_out, int out_size, void* d_ws, size_t ws_size,
                              hipStream_t stream) {
  const float* q = (const float*)d_in[0];
  const float* k = (const float*)d_in[1];
  const float* v = (const float*)d_in[2];
  float* out = (float*)d_out;

  fa_mfma_kernel<<<dim3(512), 512, 0, stream>>>(q, k, v, out);
}

// Round 9
// 205.508 us; speedup vs baseline: 2.0572x; 2.0572x over previous
//
#include <hip/hip_runtime.h>
#include <math.h>

namespace {

typedef _Float16 half8 __attribute__((ext_vector_type(8)));
typedef float floatx4 __attribute__((ext_vector_type(4)));

constexpr int kS   = 1024;
constexpr int kD   = 64;
constexpr int kPad = 72;   // 144 B row stride: 16B-aligned (b128-safe)
constexpr float kLog2e = 1.4426950408889634f;
constexpr float kThr   = 8.0f;  // defer-rescale threshold (log2 space)

union H4 { _Float16 h[4]; uint2 u2; };

__device__ __forceinline__ float fast_exp2(float x) {
#if __has_builtin(__builtin_amdgcn_exp2f)
  return __builtin_amdgcn_exp2f(x);
#else
  return exp2f(x);
#endif
}

__device__ __forceinline__ float fast_rcp(float x) {
#if __has_builtin(__builtin_amdgcn_rcpf)
  return __builtin_amdgcn_rcpf(x);
#else
  return 1.0f / x;
#endif
}

// Occupancy is pinned at 2 waves/SIMD: 64-row waves are work-limited there,
// and every 4-wave launch bound (R2/R7/R8) made the allocator give 64 arch
// regs -> massive spill. So this round cuts per-wave serial latency instead:
//  (1) speculative P pack: P = exp2(S - m_stale) written immediately; the
//      defer-rescale trigger is a LANE-LOCAL ballot (identical semantics:
//      any-lane-exceeds == row-max-exceeds); shfl max-reduce + VALU repack
//      from live S only on the rare need path (~2/16 tiles).
//  (2) l row-sum deferred to the epilogue (lane-local partials; alpha rescale
//      is linear so it commutes) -- no l shfls in the loop.
//  (3) V^T staging write was 2x over the bank phase floor (bulk of the 7.3M
//      conflict cycles): rotate 16B key-blocks by row, pos = (key>>3 + row)&7.
//      Write becomes exactly balanced; fv b128 read stays balanced.
__global__ __launch_bounds__(256, 2)
void fa_mfma_kernel(const float* __restrict__ qg, const float* __restrict__ kg,
                    const float* __restrict__ vg, float* __restrict__ og) {
  __shared__ __align__(16) _Float16 sK [2][64][kPad];  // K tiles [buf][key][d]
  __shared__ __align__(16) _Float16 sVt[2][64][kPad];  // V^T tiles [buf][d][key-swz]
  __shared__ __align__(16) _Float16 sP [256][kPad];    // P [qrow(block)][key]

  const int tid  = threadIdx.x;
  const int lane = tid & 63;
  const int w    = __builtin_amdgcn_readfirstlane(tid >> 6);
  const int quad = lane >> 4;
  const int r    = lane & 15;

  // XCD swizzle for 512 blocks: batch b's 4 q-tile blocks -> same XCD (i%8).
  const int blk = blockIdx.x;
  const int b     = (blk & 7) + 8 * (blk >> 5);  // batch 0..127
  const int qbase = ((blk >> 3) & 3) * 256;      // q-tile 0..3 (256 rows each)

  const float* qb = qg + (size_t)b * kS * kD;
  const float* kb = kg + (size_t)b * kS * kD;
  const float* vb = vg + (size_t)b * kS * kD;
  float*       ob = og + (size_t)b * kS * kD;

  // ---- Q fragments direct from global: hi/lo f16 split, pre-scaled log2e ----
  half8 fqh[4][2], fql[4][2];  // [ntq][ks]
#pragma unroll
  for (int ntq = 0; ntq < 4; ++ntq)
#pragma unroll
    for (int ks = 0; ks < 2; ++ks) {
      const float* src =
          qb + (size_t)(qbase + w * 64 + ntq * 16 + r) * kD + ks * 32 + quad * 8;
      float4 a = ((const float4*)src)[0];
      float4 c = ((const float4*)src)[1];
      float f[8] = {a.x, a.y, a.z, a.w, c.x, c.y, c.z, c.w};
#pragma unroll
      for (int j = 0; j < 8; ++j) {
        float x = f[j] * kLog2e;
        _Float16 h = (_Float16)x;
        fqh[ntq][ks][j] = h;
        fql[ntq][ks][j] = (_Float16)(x - (float)h);
      }
    }

  float m_i[4] = {-INFINITY, -INFINITY, -INFINITY, -INFINITY};
  float l_i[4] = {0.f, 0.f, 0.f, 0.f};  // lane-local partials (reduced at end)
  floatx4 O[4][4];
#pragma unroll
  for (int a = 0; a < 4; ++a)
#pragma unroll
    for (int c = 0; c < 4; ++c) O[a][c] = floatx4{0.f, 0.f, 0.f, 0.f};

  // K/V prefetch registers (one tile ahead of the LDS buffer being staged).
  const int krow = tid >> 2, kc0 = (tid & 3) * 16;   // K row-major copy
  const int vkey4 = (tid & 15) * 4;                  // V: 4 consecutive keys
  const int vd0   = (tid >> 4) * 4;                  //    x 4 dims sub-tile
  float4 kbuf[4], vbuf[4];

  auto load_kv = [&](int kt) {
    const float4* ksrc = (const float4*)(kb + (size_t)(kt * 64 + krow) * kD + kc0);
#pragma unroll
    for (int g = 0; g < 4; ++g) kbuf[g] = ksrc[g];
#pragma unroll
    for (int kk = 0; kk < 4; ++kk)
      vbuf[kk] = *(const float4*)(vb + (size_t)(kt * 64 + vkey4 + kk) * kD + vd0);
  };
  auto stage = [&](int bi) {
#pragma unroll
    for (int g = 0; g < 4; ++g) {
      float t[4] = {kbuf[g].x, kbuf[g].y, kbuf[g].z, kbuf[g].w};
      H4 hk;
#pragma unroll
      for (int j = 0; j < 4; ++j) hk.h[j] = (_Float16)t[j];
      *(uint2*)&sK[bi][krow][kc0 + g * 4] = hk.u2;
    }
    float tv[4][4];
#pragma unroll
    for (int kk = 0; kk < 4; ++kk) {
      tv[kk][0] = vbuf[kk].x; tv[kk][1] = vbuf[kk].y;
      tv[kk][2] = vbuf[kk].z; tv[kk][3] = vbuf[kk].w;
    }
#pragma unroll
    for (int j = 0; j < 4; ++j) {
      H4 hv;
#pragma unroll
      for (int kk = 0; kk < 4; ++kk) hv.h[kk] = (_Float16)tv[kk][j];
      const int row = vd0 + j;
      // block-rotation swizzle: 8-key (16B) block kb stored at (kb+row)&7
      const int col = ((((vkey4 >> 3) + row) & 7) << 3) | (vkey4 & 7);
      *(uint2*)&sVt[bi][row][col] = hv.u2;
    }
  };

  // Prologue: LDS buf0 <- tile 0; regs <- tile 1.
  load_kv(0);
  stage(0);
  load_kv(1);

  for (int kt = 0; kt < kS / 64; ++kt) {
    const int cur = kt & 1, nxt = cur ^ 1;
    __syncthreads();  // buf[cur] staged & prior reads of buf[nxt] done
    stage(nxt);                // tile kt+1 -> other buffer (overlaps compute)
    load_kv((kt + 2) & 15);    // regs <- tile kt+2 (wrap harmless)

    // ---- QK pass A (q-groups 0,1): hi+lo merged, S kept live ----
    floatx4 S0[2][4];
    __builtin_amdgcn_s_setprio(1);
#pragma unroll
    for (int mt = 0; mt < 4; ++mt) {
      half8 fk0 = *(const half8*)&sK[cur][mt * 16 + r][quad * 8];
      half8 fk1 = *(const half8*)&sK[cur][mt * 16 + r][32 + quad * 8];
#pragma unroll
      for (int g = 0; g < 2; ++g) {
        floatx4 s = {0.f, 0.f, 0.f, 0.f};
        s = __builtin_amdgcn_mfma_f32_16x16x32_f16(fk0, fqh[g][0], s, 0, 0, 0);
        s = __builtin_amdgcn_mfma_f32_16x16x32_f16(fk1, fqh[g][1], s, 0, 0, 0);
        s = __builtin_amdgcn_mfma_f32_16x16x32_f16(fk0, fql[g][0], s, 0, 0, 0);
        s = __builtin_amdgcn_mfma_f32_16x16x32_f16(fk1, fql[g][1], s, 0, 0, 0);
        S0[g][mt] = s;
      }
    }
    __builtin_amdgcn_s_setprio(0);

    // ---- speculative pack A: exp2 with stale m, write P, lane-local check ----
    {
      float rs[2] = {0.f, 0.f}, pmax[2] = {-INFINITY, -INFINITY};
#pragma unroll
      for (int g = 0; g < 2; ++g)
#pragma unroll
        for (int mt = 0; mt < 4; ++mt) {
          H4 hp;
#pragma unroll
          for (int j = 0; j < 4; ++j) {
            const float sj = S0[g][mt][j];
            pmax[g] = fmaxf(pmax[g], sj);
            const float pj = fast_exp2(sj - m_i[g]);
            rs[g] += pj;
            hp.h[j] = (_Float16)pj;
          }
          *(uint2*)&sP[w * 64 + g * 16 + r][mt * 16 + quad * 4] = hp.u2;
        }
      const unsigned long long need =
          __ballot(pmax[0] > m_i[0] + kThr || pmax[1] > m_i[1] + kThr);
      if (need) {
        float alpha[2];
#pragma unroll
        for (int g = 0; g < 2; ++g) {
          float t = pmax[g];
          t = fmaxf(t, __shfl_xor(t, 16, 64));
          t = fmaxf(t, __shfl_xor(t, 32, 64));
          const float mn = fmaxf(m_i[g], t);
          alpha[g] = fast_exp2(m_i[g] - mn);  // first tile: exp2(-inf)=0
          m_i[g] = mn;
          l_i[g] *= alpha[g];
          rs[g] = 0.f;
        }
#pragma unroll
        for (int g = 0; g < 2; ++g)
#pragma unroll
          for (int j = 0; j < 4; ++j) {
            const float a = __shfl(alpha[g], quad * 4 + j, 64);
#pragma unroll
            for (int nd = 0; nd < 4; ++nd) O[g][nd][j] *= a;
          }
        // repack from live S (VALU only), rewrite P
#pragma unroll
        for (int g = 0; g < 2; ++g)
#pragma unroll
          for (int mt = 0; mt < 4; ++mt) {
            H4 hp;
#pragma unroll
            for (int j = 0; j < 4; ++j) {
              const float pj = fast_exp2(S0[g][mt][j] - m_i[g]);
              rs[g] += pj;
              hp.h[j] = (_Float16)pj;
            }
            *(uint2*)&sP[w * 64 + g * 16 + r][mt * 16 + quad * 4] = hp.u2;
          }
      }
      l_i[0] += rs[0];
      l_i[1] += rs[1];
    }

    // ---- QK pass B (q-groups 2,3) ----
    floatx4 S1[2][4];
    __builtin_amdgcn_s_setprio(1);
#pragma unroll
    for (int mt = 0; mt < 4; ++mt) {
      half8 fk0 = *(const half8*)&sK[cur][mt * 16 + r][quad * 8];
      half8 fk1 = *(const half8*)&sK[cur][mt * 16 + r][32 + quad * 8];
#pragma unroll
      for (int g = 0; g < 2; ++g) {
        floatx4 s = {0.f, 0.f, 0.f, 0.f};
        s = __builtin_amdgcn_mfma_f32_16x16x32_f16(fk0, fqh[2 + g][0], s, 0, 0, 0);
        s = __builtin_amdgcn_mfma_f32_16x16x32_f16(fk1, fqh[2 + g][1], s, 0, 0, 0);
        s = __builtin_amdgcn_mfma_f32_16x16x32_f16(fk0, fql[2 + g][0], s, 0, 0, 0);
        s = __builtin_amdgcn_mfma_f32_16x16x32_f16(fk1, fql[2 + g][1], s, 0, 0, 0);
        S1[g][mt] = s;
      }
    }
    __builtin_amdgcn_s_setprio(0);

    // ---- PV first half: O[0],O[1] (overlaps pack B below via scheduler) ----
    __builtin_amdgcn_s_setprio(1);
#pragma unroll
    for (int ks = 0; ks < 2; ++ks) {
      half8 fp0 = *(const half8*)&sP[w * 64 + 0 * 16 + r][ks * 32 + quad * 8];
      half8 fp1 = *(const half8*)&sP[w * 64 + 1 * 16 + r][ks * 32 + quad * 8];
#pragma unroll
      for (int nd = 0; nd < 4; ++nd) {
        const int pb = ((ks * 4 + quad + r) & 7) << 3;  // swizzled V block
        half8 fv = *(const half8*)&sVt[cur][nd * 16 + r][pb];
        O[0][nd] = __builtin_amdgcn_mfma_f32_16x16x32_f16(fp0, fv, O[0][nd], 0, 0, 0);
        O[1][nd] = __builtin_amdgcn_mfma_f32_16x16x32_f16(fp1, fv, O[1][nd], 0, 0, 0);
      }
    }
    __builtin_amdgcn_s_setprio(0);

    // ---- speculative pack B (groups 2,3): VALU overlaps PV-A MFMAs ----
    {
      float rs[2] = {0.f, 0.f}, pmax[2] = {-INFINITY, -INFINITY};
#pragma unroll
      for (int g = 0; g < 2; ++g)
#pragma unroll
        for (int mt = 0; mt < 4; ++mt) {
          H4 hp;
#pragma unroll
          for (int j = 0; j < 4; ++j) {
            const float sj = S1[g][mt][j];
            pmax[g] = fmaxf(pmax[g], sj);
            const float pj = fast_exp2(sj - m_i[2 + g]);
            rs[g] += pj;
            hp.h[j] = (_Float16)pj;
          }
          *(uint2*)&sP[w * 64 + (2 + g) * 16 + r][mt * 16 + quad * 4] = hp.u2;
        }
      const unsigned long long need =
          __ballot(pmax[0] > m_i[2] + kThr || pmax[1] > m_i[3] + kThr);
      if (need) {
        float alpha[2];
#pragma unroll
        for (int g = 0; g < 2; ++g) {
          float t = pmax[g];
          t = fmaxf(t, __shfl_xor(t, 16, 64));
          t = fmaxf(t, __shfl_xor(t, 32, 64));
          const float mn = fmaxf(m_i[2 + g], t);
          alpha[g] = fast_exp2(m_i[2 + g] - mn);
          m_i[2 + g] = mn;
          l_i[2 + g] *= alpha[g];
          rs[g] = 0.f;
        }
#pragma unroll
        for (int g = 0; g < 2; ++g)
#pragma unroll
          for (int j = 0; j < 4; ++j) {
            const float a = __shfl(alpha[g], quad * 4 + j, 64);
#pragma unroll
            for (int nd = 0; nd < 4; ++nd) O[2 + g][nd][j] *= a;
          }
#pragma unroll
        for (int g = 0; g < 2; ++g)
#pragma unroll
          for (int mt = 0; mt < 4; ++mt) {
            H4 hp;
#pragma unroll
            for (int j = 0; j < 4; ++j) {
              const float pj = fast_exp2(S1[g][mt][j] - m_i[2 + g]);
              rs[g] += pj;
              hp.h[j] = (_Float16)pj;
            }
            *(uint2*)&sP[w * 64 + (2 + g) * 16 + r][mt * 16 + quad * 4] = hp.u2;
          }
      }
      l_i[2] += rs[0];
      l_i[3] += rs[1];
    }

    // ---- PV second half: O[2],O[3] ----
    __builtin_amdgcn_s_setprio(1);
#pragma unroll
    for (int ks = 0; ks < 2; ++ks) {
      half8 fp2 = *(const half8*)&sP[w * 64 + 2 * 16 + r][ks * 32 + quad * 8];
      half8 fp3 = *(const half8*)&sP[w * 64 + 3 * 16 + r][ks * 32 + quad * 8];
#pragma unroll
      for (int nd = 0; nd < 4; ++nd) {
        const int pb = ((ks * 4 + quad + r) & 7) << 3;
        half8 fv = *(const half8*)&sVt[cur][nd * 16 + r][pb];
        O[2][nd] = __builtin_amdgcn_mfma_f32_16x16x32_f16(fp2, fv, O[2][nd], 0, 0, 0);
        O[3][nd] = __builtin_amdgcn_mfma_f32_16x16x32_f16(fp3, fv, O[3][nd], 0, 0, 0);
      }
    }
    __builtin_amdgcn_s_setprio(0);
  }

  // ---- epilogue: reduce lane-local l across quads, then out = O / l ----
#pragma unroll
  for (int mtq = 0; mtq < 4; ++mtq) {
    float t = l_i[mtq];
    t += __shfl_xor(t, 16, 64);
    t += __shfl_xor(t, 32, 64);
#pragma unroll
    for (int j = 0; j < 4; ++j) {
      const float lrow = __shfl(t, quad * 4 + j, 64);
      const float linv = fast_rcp(lrow);
      float* dst =
          ob + (size_t)(qbase + w * 64 + mtq * 16 + quad * 4 + j) * kD + r;
#pragma unroll
      for (int nd = 0; nd < 4; ++nd) dst[nd * 16] = O[mtq][nd][j] * linv;
    }
  }
}

}  // namespace

extern "C" void kernel_launch(void* const* d_in, const int* in_sizes, int n_in,
                              void* d_out, int out_size, void* d_ws, size_t ws_size,
                              hipStream_t stream) {
  const float* q = (const float*)d_in[0];
  const float* k = (const float*)d_in[1];
  const float* v = (const float*)d_in[2];
  float* out = (float*)d_out;

  fa_mfma_kernel<<<dim3(512), 256, 0, stream>>>(q, k, v, out);
}

// Round 11
// 191.489 us; speedup vs baseline: 2.2078x; 1.0732x over previous
//
#include <hip/hip_runtime.h>
#include <math.h>

namespace {

typedef _Float16 half8 __attribute__((ext_vector_type(8)));
typedef float floatx4 __attribute__((ext_vector_type(4)));

constexpr int kS   = 1024;
constexpr int kD   = 64;
constexpr int kPad = 72;   // 144 B row stride: 16B-aligned (b128-safe); R9 showed
                           // all hot accesses are at the bank phase floor already
constexpr float kLog2e = 1.4426950408889634f;
constexpr float kThr   = 8.0f;  // defer-rescale threshold (log2 space)

union H4 { _Float16 h[4]; uint2 u2; };

__device__ __forceinline__ float fast_exp2(float x) {
#if __has_builtin(__builtin_amdgcn_exp2f)
  return __builtin_amdgcn_exp2f(x);
#else
  return exp2f(x);
#endif
}

__device__ __forceinline__ float fast_rcp(float x) {
#if __has_builtin(__builtin_amdgcn_rcpf)
  return __builtin_amdgcn_rcpf(x);
#else
  return 1.0f / x;
#endif
}

__device__ __forceinline__ unsigned pk2(float a, float b) {
#if __has_builtin(__builtin_amdgcn_cvt_pkrtz)
  auto h = __builtin_amdgcn_cvt_pkrtz(a, b);  // __fp16 ext_vector(2)
  return __builtin_bit_cast(unsigned, h);
#else
  H4 t; t.h[0] = (_Float16)a; t.h[1] = (_Float16)b;
  return t.u2.x;
#endif
}

// R6 skeleton (best measured 86.5us: dbuf K/V 1-barrier/tile, merged hi/lo
// MFMA chain, QK-A/SM-A/QK-B/PV-A/SM-B/PV-B interleave, (256,2), 64-row
// waves, XCD swizzle) with the softmax slimmed:
//  - lane-local ballot trigger (any-lane-exceeds == any-row-exceeds); the
//    shfl max-reduce runs only on need tiles (~2/16). Zero common-path shfls.
//  - l kept as lane-local partial, *= alpha on need tiles (exact: alpha is
//    per-row, uniform across that row's quad lanes); quad-reduced once in
//    the epilogue.
//  - tree max (depth 4, exact) instead of a 16-deep serial fmax chain.
//  - P packed with v_cvt_pkrtz (1 op/pair); K/V staging stays RNE.
// NOT repeated: R9's V swizzle (created 4-way read conflicts), speculative
// double-pack (spilled), any 4-wave launch bound (R2/R7/R8: allocator gives
// 64 arch regs and spills catastrophically).
__global__ __launch_bounds__(256, 2)
void fa_mfma_kernel(const float* __restrict__ qg, const float* __restrict__ kg,
                    const float* __restrict__ vg, float* __restrict__ og) {
  __shared__ __align__(16) _Float16 sK [2][64][kPad];  // K tiles [buf][key][d]
  __shared__ __align__(16) _Float16 sVt[2][64][kPad];  // V^T tiles [buf][d][key]
  __shared__ __align__(16) _Float16 sP [256][kPad];    // P [qrow(block)][key]

  const int tid  = threadIdx.x;
  const int lane = tid & 63;
  const int w    = __builtin_amdgcn_readfirstlane(tid >> 6);
  const int quad = lane >> 4;
  const int r    = lane & 15;

  // XCD swizzle for 512 blocks: batch b's 4 q-tile blocks -> same XCD (i%8).
  const int blk = blockIdx.x;
  const int b     = (blk & 7) + 8 * (blk >> 5);  // batch 0..127
  const int qbase = ((blk >> 3) & 3) * 256;      // q-tile 0..3 (256 rows each)

  const float* qb = qg + (size_t)b * kS * kD;
  const float* kb = kg + (size_t)b * kS * kD;
  const float* vb = vg + (size_t)b * kS * kD;
  float*       ob = og + (size_t)b * kS * kD;

  // ---- Q fragments direct from global: hi/lo f16 split, pre-scaled log2e ----
  half8 fqh[4][2], fql[4][2];  // [ntq][ks]
#pragma unroll
  for (int ntq = 0; ntq < 4; ++ntq)
#pragma unroll
    for (int ks = 0; ks < 2; ++ks) {
      const float* src =
          qb + (size_t)(qbase + w * 64 + ntq * 16 + r) * kD + ks * 32 + quad * 8;
      float4 a = ((const float4*)src)[0];
      float4 c = ((const float4*)src)[1];
      float f[8] = {a.x, a.y, a.z, a.w, c.x, c.y, c.z, c.w};
#pragma unroll
      for (int j = 0; j < 8; ++j) {
        float x = f[j] * kLog2e;
        _Float16 h = (_Float16)x;
        fqh[ntq][ks][j] = h;
        fql[ntq][ks][j] = (_Float16)(x - (float)h);
      }
    }

  float m_i[4] = {-INFINITY, -INFINITY, -INFINITY, -INFINITY};
  float l_i[4] = {0.f, 0.f, 0.f, 0.f};  // lane-local partials (epilogue-reduced)
  floatx4 O[4][4];
#pragma unroll
  for (int a = 0; a < 4; ++a)
#pragma unroll
    for (int c = 0; c < 4; ++c) O[a][c] = floatx4{0.f, 0.f, 0.f, 0.f};

  // K/V prefetch registers (one tile ahead of the LDS buffer being staged).
  const int krow = tid >> 2, kc0 = (tid & 3) * 16;   // K row-major copy
  const int vkey4 = (tid & 15) * 4;                  // V: 4 consecutive keys
  const int vd0   = (tid >> 4) * 4;                  //    x 4 dims sub-tile
  float4 kbuf[4], vbuf[4];

  auto load_kv = [&](int kt) {
    const float4* ksrc = (const float4*)(kb + (size_t)(kt * 64 + krow) * kD + kc0);
#pragma unroll
    for (int g = 0; g < 4; ++g) kbuf[g] = ksrc[g];
#pragma unroll
    for (int kk = 0; kk < 4; ++kk)
      vbuf[kk] = *(const float4*)(vb + (size_t)(kt * 64 + vkey4 + kk) * kD + vd0);
  };
  auto stage = [&](int bi) {
#pragma unroll
    for (int g = 0; g < 4; ++g) {
      float t[4] = {kbuf[g].x, kbuf[g].y, kbuf[g].z, kbuf[g].w};
      H4 hk;
#pragma unroll
      for (int j = 0; j < 4; ++j) hk.h[j] = (_Float16)t[j];
      *(uint2*)&sK[bi][krow][kc0 + g * 4] = hk.u2;
    }
    float tv[4][4];
#pragma unroll
    for (int kk = 0; kk < 4; ++kk) {
      tv[kk][0] = vbuf[kk].x; tv[kk][1] = vbuf[kk].y;
      tv[kk][2] = vbuf[kk].z; tv[kk][3] = vbuf[kk].w;
    }
#pragma unroll
    for (int j = 0; j < 4; ++j) {
      H4 hv;
#pragma unroll
      for (int kk = 0; kk < 4; ++kk) hv.h[kk] = (_Float16)tv[kk][j];
      *(uint2*)&sVt[bi][vd0 + j][vkey4] = hv.u2;
    }
  };

  // ---- slim softmax for a pass of 2 q-groups (base = first group idx) ----
  auto softmax2 = [&](floatx4 (&S)[2][4], int base) {
    float pmax[2];
#pragma unroll
    for (int g = 0; g < 2; ++g) {  // tree max, depth 4, exact
      float a0 = fmaxf(fmaxf(S[g][0][0], S[g][0][1]), fmaxf(S[g][0][2], S[g][0][3]));
      float a1 = fmaxf(fmaxf(S[g][1][0], S[g][1][1]), fmaxf(S[g][1][2], S[g][1][3]));
      float a2 = fmaxf(fmaxf(S[g][2][0], S[g][2][1]), fmaxf(S[g][2][2], S[g][2][3]));
      float a3 = fmaxf(fmaxf(S[g][3][0], S[g][3][1]), fmaxf(S[g][3][2], S[g][3][3]));
      pmax[g] = fmaxf(fmaxf(a0, a1), fmaxf(a2, a3));
    }
    // lane-local trigger: any lane exceeding == any row's max exceeding
    const unsigned long long need =
        __ballot(pmax[0] > m_i[base] + kThr || pmax[1] > m_i[base + 1] + kThr);
    if (need) {  // rare (~2/16 tiles): full reduce + rescale
      float alpha[2];
#pragma unroll
      for (int g = 0; g < 2; ++g) {
        float t = pmax[g];
        t = fmaxf(t, __shfl_xor(t, 16, 64));
        t = fmaxf(t, __shfl_xor(t, 32, 64));
        const float mn = fmaxf(m_i[base + g], t);
        alpha[g] = fast_exp2(m_i[base + g] - mn);  // first tile: exp2(-inf)=0
        m_i[base + g] = mn;
        l_i[base + g] *= alpha[g];
      }
#pragma unroll
      for (int g = 0; g < 2; ++g)
#pragma unroll
        for (int j = 0; j < 4; ++j) {
          const float a = __shfl(alpha[g], quad * 4 + j, 64);
#pragma unroll
          for (int nd = 0; nd < 4; ++nd) O[base + g][nd][j] *= a;
        }
    }
    // pack P with final m (single write); l partial stays lane-local
#pragma unroll
    for (int g = 0; g < 2; ++g) {
      float rs = 0.f;
#pragma unroll
      for (int mt = 0; mt < 4; ++mt) {
        float p0 = fast_exp2(S[g][mt][0] - m_i[base + g]);
        float p1 = fast_exp2(S[g][mt][1] - m_i[base + g]);
        float p2 = fast_exp2(S[g][mt][2] - m_i[base + g]);
        float p3 = fast_exp2(S[g][mt][3] - m_i[base + g]);
        rs += (p0 + p1) + (p2 + p3);
        uint2 u; u.x = pk2(p0, p1); u.y = pk2(p2, p3);
        *(uint2*)&sP[w * 64 + (base + g) * 16 + r][mt * 16 + quad * 4] = u;
      }
      l_i[base + g] += rs;
    }
  };

  // Prologue: LDS buf0 <- tile 0; regs <- tile 1.
  load_kv(0);
  stage(0);
  load_kv(1);

  for (int kt = 0; kt < kS / 64; ++kt) {
    const int cur = kt & 1, nxt = cur ^ 1;
    __syncthreads();  // buf[cur] staged & prior reads of buf[nxt] done
    stage(nxt);                // tile kt+1 -> other buffer (overlaps compute)
    load_kv((kt + 2) & 15);    // regs <- tile kt+2 (wrap harmless)

    // ---- QK pass A (q-groups 0,1): hi+lo merged into one accumulator ----
    floatx4 S0[2][4];
    __builtin_amdgcn_s_setprio(1);
#pragma unroll
    for (int mt = 0; mt < 4; ++mt) {
      half8 fk0 = *(const half8*)&sK[cur][mt * 16 + r][quad * 8];
      half8 fk1 = *(const half8*)&sK[cur][mt * 16 + r][32 + quad * 8];
#pragma unroll
      for (int g = 0; g < 2; ++g) {
        floatx4 s = {0.f, 0.f, 0.f, 0.f};
        s = __builtin_amdgcn_mfma_f32_16x16x32_f16(fk0, fqh[g][0], s, 0, 0, 0);
        s = __builtin_amdgcn_mfma_f32_16x16x32_f16(fk1, fqh[g][1], s, 0, 0, 0);
        s = __builtin_amdgcn_mfma_f32_16x16x32_f16(fk0, fql[g][0], s, 0, 0, 0);
        s = __builtin_amdgcn_mfma_f32_16x16x32_f16(fk1, fql[g][1], s, 0, 0, 0);
        S0[g][mt] = s;
      }
    }
    __builtin_amdgcn_s_setprio(0);

    softmax2(S0, 0);

    // ---- QK pass B (q-groups 2,3) — hides SM-A's P-write latency ----
    floatx4 S1[2][4];
    __builtin_amdgcn_s_setprio(1);
#pragma unroll
    for (int mt = 0; mt < 4; ++mt) {
      half8 fk0 = *(const half8*)&sK[cur][mt * 16 + r][quad * 8];
      half8 fk1 = *(const half8*)&sK[cur][mt * 16 + r][32 + quad * 8];
#pragma unroll
      for (int g = 0; g < 2; ++g) {
        floatx4 s = {0.f, 0.f, 0.f, 0.f};
        s = __builtin_amdgcn_mfma_f32_16x16x32_f16(fk0, fqh[2 + g][0], s, 0, 0, 0);
        s = __builtin_amdgcn_mfma_f32_16x16x32_f16(fk1, fqh[2 + g][1], s, 0, 0, 0);
        s = __builtin_amdgcn_mfma_f32_16x16x32_f16(fk0, fql[2 + g][0], s, 0, 0, 0);
        s = __builtin_amdgcn_mfma_f32_16x16x32_f16(fk1, fql[2 + g][1], s, 0, 0, 0);
        S1[g][mt] = s;
      }
    }
    __builtin_amdgcn_s_setprio(0);

    // ---- PV first half: O[0],O[1] ----
    __builtin_amdgcn_s_setprio(1);
#pragma unroll
    for (int ks = 0; ks < 2; ++ks) {
      half8 fp0 = *(const half8*)&sP[w * 64 + 0 * 16 + r][ks * 32 + quad * 8];
      half8 fp1 = *(const half8*)&sP[w * 64 + 1 * 16 + r][ks * 32 + quad * 8];
#pragma unroll
      for (int nd = 0; nd < 4; ++nd) {
        half8 fv = *(const half8*)&sVt[cur][nd * 16 + r][ks * 32 + quad * 8];
        O[0][nd] = __builtin_amdgcn_mfma_f32_16x16x32_f16(fp0, fv, O[0][nd], 0, 0, 0);
        O[1][nd] = __builtin_amdgcn_mfma_f32_16x16x32_f16(fp1, fv, O[1][nd], 0, 0, 0);
      }
    }
    __builtin_amdgcn_s_setprio(0);

    softmax2(S1, 2);  // VALU overlaps PV-A's MFMAs

    // ---- PV second half: O[2],O[3] ----
    __builtin_amdgcn_s_setprio(1);
#pragma unroll
    for (int ks = 0; ks < 2; ++ks) {
      half8 fp2 = *(const half8*)&sP[w * 64 + 2 * 16 + r][ks * 32 + quad * 8];
      half8 fp3 = *(const half8*)&sP[w * 64 + 3 * 16 + r][ks * 32 + quad * 8];
#pragma unroll
      for (int nd = 0; nd < 4; ++nd) {
        half8 fv = *(const half8*)&sVt[cur][nd * 16 + r][ks * 32 + quad * 8];
        O[2][nd] = __builtin_amdgcn_mfma_f32_16x16x32_f16(fp2, fv, O[2][nd], 0, 0, 0);
        O[3][nd] = __builtin_amdgcn_mfma_f32_16x16x32_f16(fp3, fv, O[3][nd], 0, 0, 0);
      }
    }
    __builtin_amdgcn_s_setprio(0);
  }

  // ---- epilogue: quad-reduce lane-local l, then out = O / l ----
#pragma unroll
  for (int mtq = 0; mtq < 4; ++mtq) {
    float t = l_i[mtq];
    t += __shfl_xor(t, 16, 64);
    t += __shfl_xor(t, 32, 64);
#pragma unroll
    for (int j = 0; j < 4; ++j) {
      const float lrow = __shfl(t, quad * 4 + j, 64);
      const float linv = fast_rcp(lrow);
      float* dst =
          ob + (size_t)(qbase + w * 64 + mtq * 16 + quad * 4 + j) * kD + r;
#pragma unroll
      for (int nd = 0; nd < 4; ++nd) dst[nd * 16] = O[mtq][nd][j] * linv;
    }
  }
}

}  // namespace

extern "C" void kernel_launch(void* const* d_in, const int* in_sizes, int n_in,
                              void* d_out, int out_size, void* d_ws, size_t ws_size,
                              hipStream_t stream) {
  const float* q = (const float*)d_in[0];
  const float* k = (const float*)d_in[1];
  const float* v = (const float*)d_in[2];
  float* out = (float*)d_out;

  fa_mfma_kernel<<<dim3(512), 256, 0, stream>>>(q, k, v, out);
}